// Round 6
// baseline (306.986 us; speedup 1.0000x reference)
//
#include <hip/hip_runtime.h>

// ---------------------------------------------------------------------------
// qkv = x@W_attn; RoPE(q,k); flash-attn; y@W_proj
// B=2, T=2048, C=1024, H=16, HD=64.  I/O fp32; internal tensors bf16.
//
// R17 (R16 unmeasured — broker down — kept verbatim after a correctness
// re-audit; one zero-risk addition):
//  * [R16] attn KVBLK=128 (nkt=qt/2+1), unconditional causal mask, K/V
//    register prefetch (T14) of the next tile after the staging barrier.
//  * [R17] T5: s_setprio(1) around attn's QK^T and PV MFMA clusters.
//    With the prefetch split, co-resident waves sit in different phases
//    (load-issuing vs MFMA) — the regime where setprio measured +4-7% on
//    attn (m191).  Pure scheduling hint; no semantic effect.
//  * everything else byte-identical to R15/R16 (gemm global_load_lds
//    swizzled kernels, rope table, hoisted Wp, balanced LPT remap).
// ---------------------------------------------------------------------------

typedef __attribute__((ext_vector_type(8))) short short8;   // 8 bf16 = 4 VGPRs
typedef __attribute__((ext_vector_type(4))) float floatx4;  // MFMA C/D frag

__device__ __forceinline__ ushort f2bf(float f) {
    unsigned x = __float_as_uint(f);
    x += 0x7fffu + ((x >> 16) & 1u);   // round-to-nearest-even
    return (ushort)(x >> 16);
}
__device__ __forceinline__ float bf2f(ushort u) {
    return __uint_as_float(((unsigned)u) << 16);
}

#define MFMA16(a, b, c) __builtin_amdgcn_mfma_f32_16x16x32_bf16((a), (b), (c), 0, 0, 0)

// async global->LDS, 16 bytes per lane.  LDS dest must be wave-uniform base;
// HW writes base + lane*16.  Global src is per-lane.
__device__ __forceinline__ void glds16(const ushort* g, ushort* l) {
    __builtin_amdgcn_global_load_lds(
        (const __attribute__((address_space(1))) unsigned int*)g,
        (__attribute__((address_space(3))) unsigned int*)l, 16, 0, 0);
}

// ---------------------------------------------------------------------------
// Transpose + cvt: src f32 [R][C] -> dst bf16 [C][R].  32x32 tiles via LDS.
// ---------------------------------------------------------------------------
__global__ __launch_bounds__(256) void tp_k(const float* __restrict__ src,
                                            ushort* __restrict__ dst,
                                            int R, int C) {
    __shared__ ushort t[32][34];
    const int c0 = blockIdx.x * 32, r0 = blockIdx.y * 32;
    const int tr = threadIdx.x >> 5, tc = threadIdx.x & 31;
#pragma unroll
    for (int j = 0; j < 4; j++)
        t[tr + j * 8][tc] = f2bf(src[(size_t)(r0 + tr + j * 8) * C + c0 + tc]);
    __syncthreads();
#pragma unroll
    for (int j = 0; j < 4; j++)
        dst[(size_t)(c0 + tr + j * 8) * R + r0 + tc] = t[tc][tr + j * 8];
}

// ---------------------------------------------------------------------------
// cvt: f32 -> bf16, 4 elems/thread.
// ---------------------------------------------------------------------------
__global__ __launch_bounds__(256) void cvt_k(const float* __restrict__ src,
                                             ushort* __restrict__ dst) {
    const size_t i = ((size_t)blockIdx.x * 256 + threadIdx.x) * 4;
    float4 t4 = *(const float4*)&src[i];
    *(ushort4*)&dst[i] = make_ushort4(f2bf(t4.x), f2bf(t4.y), f2bf(t4.z), f2bf(t4.w));
}

// ---------------------------------------------------------------------------
// trig table: tab[t][j] = (cos(t * 10000^(-j/32)), sin(...)), f64 math
// identical to the original in-rope computation (bit-identical results).
// ---------------------------------------------------------------------------
__global__ __launch_bounds__(256) void trig_k(float2* __restrict__ tab) {
    const int idx = blockIdx.x * 256 + threadIdx.x;   // [0, 65536)
    const int t = idx >> 5, j = idx & 31;
    const double inv = pow(10000.0, -(double)j / 32.0);
    const double ang = (double)t * inv;
    tab[idx] = make_float2((float)cos(ang), (float)sin(ang));
}

// ---------------------------------------------------------------------------
// GEMM1 (one batch): qkv = xb[2048][1024](bf16) @ WaT^T (Bt bf16 [3072][1024])
//   -> q: [H,T,HD]  k: [H,T,HD]  v^T: [H,HD,T]  (bf16)
// R15: 128(m)x64(n) tile, BK=64, global_load_lds staging, swizzled LDS.
// ---------------------------------------------------------------------------
__global__ __launch_bounds__(256, 3) void gemm1_qkv_k(const ushort* __restrict__ Ab,
                                                      const ushort* __restrict__ Bt,
                                                      ushort* __restrict__ qb,
                                                      ushort* __restrict__ kb,
                                                      ushort* __restrict__ vtb) {
    __shared__ __align__(16) ushort As[128 * 64];  // 16 KB, linear+swizzled
    __shared__ __align__(16) ushort Bs[64 * 64];   // 8 KB
    const int tid = threadIdx.x;
    const int m0 = blockIdx.y * 128, n0 = blockIdx.x * 64;
    const int w = tid >> 6, lane = tid & 63, quad = lane >> 4, l16 = lane & 15;
    const int wr = w >> 1, wc = w & 1;
    const int K = 1024;
    const int srow = lane >> 3, sslot = lane & 7;  // staging sub-row / slot

    floatx4 acc[4][2];
#pragma unroll
    for (int mt = 0; mt < 4; mt++)
#pragma unroll
        for (int nt = 0; nt < 2; nt++) acc[mt][nt] = (floatx4){0.f, 0.f, 0.f, 0.f};

    for (int k0 = 0; k0 < K; k0 += 64) {
        __syncthreads();   // all waves done reading prev tile
#pragma unroll
        for (int jj = 0; jj < 4; jj++) {
            const int reg = jj * 4 + w;
            const int row = reg * 8 + srow;
            const int cs = sslot ^ (row & 7);
            glds16(&Ab[(size_t)(m0 + row) * K + k0 + cs * 8], &As[reg * 512]);
        }
#pragma unroll
        for (int jj = 0; jj < 2; jj++) {
            const int reg = jj * 4 + w;
            const int row = reg * 8 + srow;
            const int cs = sslot ^ (row & 7);
            glds16(&Bt[(size_t)(n0 + row) * K + k0 + cs * 8], &Bs[reg * 512]);
        }
        __syncthreads();   // compiler drains vmcnt(0) before barrier

#pragma unroll
        for (int kk = 0; kk < 2; kk++) {
            short8 af[4], bfr[2];
#pragma unroll
            for (int mt = 0; mt < 4; mt++) {
                const int row = wr * 64 + mt * 16 + l16;
                const int slot = ((kk << 2) | quad) ^ (row & 7);
                af[mt] = *(short8*)&As[row * 64 + slot * 8];
            }
#pragma unroll
            for (int nt = 0; nt < 2; nt++) {
                const int row = wc * 32 + nt * 16 + l16;
                const int slot = ((kk << 2) | quad) ^ (row & 7);
                bfr[nt] = *(short8*)&Bs[row * 64 + slot * 8];
            }
#pragma unroll
            for (int mt = 0; mt < 4; mt++)
#pragma unroll
                for (int nt = 0; nt < 2; nt++) acc[mt][nt] = MFMA16(af[mt], bfr[nt], acc[mt][nt]);
        }
    }

    // Epilogue [R5-R10 verified formulas; nt bound 2, wave n-stride 32]
#pragma unroll
    for (int nt = 0; nt < 2; nt++) {
        const int n = n0 + wc * 32 + nt * 16 + l16;
        const int seg = n >> 10;          // 0=q 1=k 2=v
        const int cn = n & 1023;
        const int h = cn >> 6, d = cn & 63;
#pragma unroll
        for (int mt = 0; mt < 4; mt++) {
#pragma unroll
            for (int r = 0; r < 4; r++) {
                const int t = m0 + wr * 64 + mt * 16 + quad * 4 + r;
                const ushort v = f2bf(acc[mt][nt][r]);
                if (seg == 0)      qb[((size_t)h * 2048 + t) * 64 + d] = v;
                else if (seg == 1) kb[((size_t)h * 2048 + t) * 64 + d] = v;
                else               vtb[((size_t)h * 64 + d) * 2048 + t] = v;
            }
        }
    }
}

// ---------------------------------------------------------------------------
// RoPE (roll variant), table-based trig.  Math identical to verified R5-R11.
// ---------------------------------------------------------------------------
__global__ __launch_bounds__(256) void rope_k(ushort* __restrict__ q,
                                              ushort* __restrict__ k,
                                              const float2* __restrict__ tab) {
    const int wid = blockIdx.x * 4 + (threadIdx.x >> 6);  // row = h*2048 + t
    const int lane = threadIdx.x & 63;
    const int t = wid & 2047;
    const float2 cs = tab[t * 32 + (lane & 31)];
    const float c = cs.x;
    const float s = cs.y;
    const size_t base = (size_t)wid * 64;

    float qv = bf2f(q[base + lane]);
    float qp = __shfl(qv, (lane + 63) & 63, 64);
    q[base + lane] = f2bf(qv * c + qp * s);

    float kv = bf2f(k[base + lane]);
    float kp = __shfl(kv, (lane + 63) & 63, 64);
    k[base + lane] = f2bf(kv * c + kp * s);
}

// ---------------------------------------------------------------------------
// Flash attention (causal), transposed form.  [R10-verified frag math]
// R12: one q-tile per block (grid 512) -> 2 blocks/CU.
// R13: no barrier between per-wave Ps write/read.
// R14: balanced qt remap (CU pairs sum to const 17 tiles).
// R16: KVBLK=128, unconditional causal mask, K/V register prefetch (T14).
// R17: s_setprio(1) around QK^T and PV MFMA clusters (T5).
// ---------------------------------------------------------------------------
__global__ __launch_bounds__(256, 2) void attn_k(const ushort* __restrict__ q,
                                                 const ushort* __restrict__ k,
                                                 const ushort* __restrict__ vt,
                                                 ushort* __restrict__ y) {
    __shared__ __align__(16) ushort Ks[128][72];    // [key][d]   18 KB
    __shared__ __align__(16) ushort Vs[64][136];    // [d][key]   17 KB (V^T)
    __shared__ __align__(16) ushort Ps[4][16][136]; // per-wave P^T [qrow][key]

    const int bid = blockIdx.x;
    // blocks 0..255: qt = 31,30,..,16 (16 heads each); 256..511: qt = 0,1,..,15
    const int qt = (bid < 256) ? (31 - (bid >> 4)) : ((bid >> 4) - 16);
    const int h = bid & 15;
    const int tid = threadIdx.x, w = tid >> 6, lane = tid & 63;
    const int quad = lane >> 4, l16 = lane & 15;

    const int q0 = qt * 64;
    const int qrow = q0 + w * 16 + l16;
    const int nkt = (qt >> 1) + 1;     // 128-key tiles (keys past causal edge
                                       // are in-bounds and masked)

    short8 qa0, qa1;
    {
        const ushort* qp = q + ((size_t)h * 2048 + qrow) * 64 + quad * 8;
        qa0 = *(const short8*)(qp);
        qa1 = *(const short8*)(qp + 32);
    }

    floatx4 O[4];
#pragma unroll
    for (int dt = 0; dt < 4; dt++) O[dt] = (floatx4){0.f, 0.f, 0.f, 0.f};
    float M = -30000.f, L = 0.f;

    // prefetch tile 0 into registers
    uint4 kR[4], vR[4];
#pragma unroll
    for (int jj = 0; jj < 4; jj++) {
        const int flat = (tid + jj * 256) * 8;
        const int r = flat >> 6, c = flat & 63;
        kR[jj] = *(const uint4*)&k[((size_t)h * 2048 + r) * 64 + c];
        const int d = flat >> 7, key = flat & 127;
        vR[jj] = *(const uint4*)&vt[((size_t)h * 64 + d) * 2048 + key];
    }

    for (int kt2 = 0; kt2 < nkt; kt2++) {
        const int kbase = kt2 * 128;
        __syncthreads();   // all waves done reading prev tile's LDS
#pragma unroll
        for (int jj = 0; jj < 4; jj++) {
            const int flat = (tid + jj * 256) * 8;
            const int r = flat >> 6, c = flat & 63;
            *(uint4*)&Ks[r][c] = kR[jj];
            const int d = flat >> 7, key = flat & 127;
            *(uint4*)&Vs[d][key] = vR[jj];
        }
        __syncthreads();   // staging complete

        // T14: issue next tile's loads now; latency hides under compute.
        if (kt2 + 1 < nkt) {
            const int kb2 = kbase + 128;
#pragma unroll
            for (int jj = 0; jj < 4; jj++) {
                const int flat = (tid + jj * 256) * 8;
                const int r = flat >> 6, c = flat & 63;
                kR[jj] = *(const uint4*)&k[((size_t)h * 2048 + kb2 + r) * 64 + c];
                const int d = flat >> 7, key = flat & 127;
                vR[jj] = *(const uint4*)&vt[((size_t)h * 64 + d) * 2048 + kb2 + key];
            }
        }

        floatx4 s[8];
        __builtin_amdgcn_s_setprio(1);   // T5: favor MFMA-issuing wave
#pragma unroll
        for (int nt = 0; nt < 8; nt++) {
            short8 ka0 = *(short8*)&Ks[nt * 16 + l16][quad * 8];
            short8 ka1 = *(short8*)&Ks[nt * 16 + l16][32 + quad * 8];
            floatx4 z = (floatx4){0.f, 0.f, 0.f, 0.f};
            z = MFMA16(ka0, qa0, z);
            z = MFMA16(ka1, qa1, z);
            s[nt] = z;
        }
        __builtin_amdgcn_s_setprio(0);

        // scale + unconditional causal mask
#pragma unroll
        for (int nt = 0; nt < 8; nt++)
#pragma unroll
            for (int r = 0; r < 4; r++) {
                const int kidx = kbase + nt * 16 + quad * 4 + r;
                const float vv = s[nt][r] * 0.125f;
                s[nt][r] = (kidx > qrow) ? -30000.f : vv;
            }

        float mx = -30000.f;
#pragma unroll
        for (int nt = 0; nt < 8; nt++)
#pragma unroll
            for (int r = 0; r < 4; r++) mx = fmaxf(mx, s[nt][r]);
        mx = fmaxf(mx, __shfl_xor(mx, 16, 64));
        mx = fmaxf(mx, __shfl_xor(mx, 32, 64));
        const float Mn = fmaxf(M, mx);
        const float alpha = __expf(M - Mn);
        float sum = 0.f;
#pragma unroll
        for (int nt = 0; nt < 8; nt++)
#pragma unroll
            for (int r = 0; r < 4; r++) {
                const float pv = __expf(s[nt][r] - Mn);
                s[nt][r] = pv;
                sum += pv;
            }
        sum += __shfl_xor(sum, 16, 64);
        sum += __shfl_xor(sum, 32, 64);
        L = L * alpha + sum;
        M = Mn;
#pragma unroll
        for (int dt = 0; dt < 4; dt++) O[dt] *= alpha;

#pragma unroll
        for (int nt = 0; nt < 8; nt++) {
            ushort4 pk = make_ushort4(f2bf(s[nt][0]), f2bf(s[nt][1]),
                                      f2bf(s[nt][2]), f2bf(s[nt][3]));
            *(ushort4*)&Ps[w][l16][nt * 16 + quad * 4] = pk;
        }
        // no barrier: Ps[w] is written and read only by wave w; in-wave DS
        // ordering is enforced by the compiler's lgkmcnt tracking.

        short8 pb[4];
#pragma unroll
        for (int ks = 0; ks < 4; ks++)
            pb[ks] = *(short8*)&Ps[w][l16][ks * 32 + quad * 8];
        __builtin_amdgcn_s_setprio(1);   // T5: PV MFMA cluster
#pragma unroll
        for (int dt = 0; dt < 4; dt++) {
#pragma unroll
            for (int ks = 0; ks < 4; ks++) {
                short8 va = *(short8*)&Vs[dt * 16 + l16][ks * 32 + quad * 8];
                O[dt] = MFMA16(va, pb[ks], O[dt]);
            }
        }
        __builtin_amdgcn_s_setprio(0);
    }

    const float rl = 1.0f / L;
#pragma unroll
    for (int dt = 0; dt < 4; dt++) {
        ushort4 o4 = make_ushort4(f2bf(O[dt][0] * rl), f2bf(O[dt][1] * rl),
                                  f2bf(O[dt][2] * rl), f2bf(O[dt][3] * rl));
        *(ushort4*)&y[(size_t)qrow * 1024 + h * 64 + dt * 16 + quad * 4] = o4;
    }
}

// ---------------------------------------------------------------------------
// GEMM2 (one batch): out(f32) = y[2048][1024](bf16) @ WpT^T (bf16 [1024][1024])
// R15: 64x64 tile (grid 16x32 = 512 blocks = 2/CU), BK=64, global_load_lds
// staging, swizzled LDS — same machinery as gemm1.
// ---------------------------------------------------------------------------
__global__ __launch_bounds__(256, 2) void gemm2_proj_k(const ushort* __restrict__ Y,
                                                       const ushort* __restrict__ Bt,
                                                       float* __restrict__ out) {
    __shared__ __align__(16) ushort As[64 * 64];   // 8 KB, linear+swizzled
    __shared__ __align__(16) ushort Bs[64 * 64];   // 8 KB
    const int tid = threadIdx.x;
    const int m0 = blockIdx.y * 64, n0 = blockIdx.x * 64;
    const int w = tid >> 6, lane = tid & 63, quad = lane >> 4, l16 = lane & 15;
    const int wr = w >> 1, wc = w & 1;
    const int K = 1024;
    const int srow = lane >> 3, sslot = lane & 7;

    floatx4 acc[2][2];
#pragma unroll
    for (int mt = 0; mt < 2; mt++)
#pragma unroll
        for (int nt = 0; nt < 2; nt++) acc[mt][nt] = (floatx4){0.f, 0.f, 0.f, 0.f};

    for (int k0 = 0; k0 < K; k0 += 64) {
        __syncthreads();
#pragma unroll
        for (int jj = 0; jj < 2; jj++) {
            const int reg = jj * 4 + w;
            const int row = reg * 8 + srow;
            const int cs = sslot ^ (row & 7);
            glds16(&Y[(size_t)(m0 + row) * K + k0 + cs * 8], &As[reg * 512]);
            glds16(&Bt[(size_t)(n0 + row) * K + k0 + cs * 8], &Bs[reg * 512]);
        }
        __syncthreads();

#pragma unroll
        for (int kk = 0; kk < 2; kk++) {
            short8 af[2], bfr[2];
#pragma unroll
            for (int mt = 0; mt < 2; mt++) {
                const int row = wr * 32 + mt * 16 + l16;
                const int slot = ((kk << 2) | quad) ^ (row & 7);
                af[mt] = *(short8*)&As[row * 64 + slot * 8];
            }
#pragma unroll
            for (int nt = 0; nt < 2; nt++) {
                const int row = wc * 32 + nt * 16 + l16;
                const int slot = ((kk << 2) | quad) ^ (row & 7);
                bfr[nt] = *(short8*)&Bs[row * 64 + slot * 8];
            }
#pragma unroll
            for (int mt = 0; mt < 2; mt++)
#pragma unroll
                for (int nt = 0; nt < 2; nt++) acc[mt][nt] = MFMA16(af[mt], bfr[nt], acc[mt][nt]);
        }
    }

#pragma unroll
    for (int mt = 0; mt < 2; mt++)
#pragma unroll
        for (int nt = 0; nt < 2; nt++) {
            const int n = n0 + wc * 32 + nt * 16 + l16;
#pragma unroll
            for (int r = 0; r < 4; r++) {
                const int m = m0 + wr * 32 + mt * 16 + quad * 4 + r;
                out[(size_t)m * 1024 + n] = acc[mt][nt][r];
            }
        }
}

// ---------------------------------------------------------------------------
extern "C" void kernel_launch(void* const* d_in, const int* in_sizes, int n_in,
                              void* d_out, int out_size, void* d_ws, size_t ws_size,
                              hipStream_t stream) {
    const float* x  = (const float*)d_in[0];   // [2,2048,1024] f32
    const float* Wa = (const float*)d_in[1];   // [1024,3072]  f32
    const float* Wp = (const float*)d_in[2];   // [1024,1024]  f32
    float* out = (float*)d_out;                // [2,2048,1024] f32

    const size_t PB = (size_t)2048 * 1024;     // per-batch elements
    ushort* qb  = (ushort*)d_ws;               // 4 MB bf16 q  [H,T,HD]
    ushort* kb  = qb + PB;                     // 4 MB bf16 k  [H,T,HD]
    ushort* vtb = kb + PB;                     // 4 MB bf16 v^T[H,HD,T]
    ushort* yb  = vtb + PB;                    // 4 MB bf16 y [T,C] / x_bf16
    ushort* wtA = (ushort*)(out + PB);         // 6 MB W_attn^T bf16 (d_out b1
                                               //  half; dead until gemm2-b1,
                                               //  which fully overwrites it)
    float2* tab = (float2*)(wtA + (size_t)3 * 1024 * 1024);
                                               // 512 KB trig table, bytes
                                               //  [14MB,14.5MB) of d_out; last
                                               //  read by rope-b1, overwritten
                                               //  only by gemm2-b1

    // W_proj^T: hoisted to stable ws tail (d_ws+16MB) when it fits; else the
    // per-batch qb-slot path (wtP regenerated each batch, over dead q).
    const bool hoistWp = ws_size >= (size_t)18 * 1024 * 1024;
    ushort* wtP_stable = yb + PB;              // d_ws + 16MB (only if hoistWp)

    tp_k<<<dim3(96, 32), 256, 0, stream>>>(Wa, wtA, 1024, 3072);
    trig_k<<<dim3(256), 256, 0, stream>>>(tab);
    if (hoistWp)
        tp_k<<<dim3(32, 32), 256, 0, stream>>>(Wp, wtP_stable, 1024, 1024);

    for (int b = 0; b < 2; b++) {
        cvt_k<<<dim3(2048), 256, 0, stream>>>(x + b * PB, yb);        // xb in yb slot
        gemm1_qkv_k<<<dim3(48, 16), 256, 0, stream>>>(yb, wtA, qb, kb, vtb);
        rope_k<<<dim3(8192), 256, 0, stream>>>(qb, kb, tab);
        attn_k<<<dim3(512), 256, 0, stream>>>(qb, kb, vtb, yb);       // y over xb
        if (hoistWp) {
            gemm2_proj_k<<<dim3(16, 32), 256, 0, stream>>>(yb, wtP_stable, out + b * PB);
        } else {
            tp_k<<<dim3(32, 32), 256, 0, stream>>>(Wp, qb, 1024, 1024);  // over dead q
            gemm2_proj_k<<<dim3(16, 32), 256, 0, stream>>>(yb, qb, out + b * PB);
        }
    }
}

// Round 8
// 259.082 us; speedup vs baseline: 1.1849x; 1.1849x over previous
//
#include <hip/hip_runtime.h>

// ---------------------------------------------------------------------------
// qkv = x@W_attn; RoPE(q,k); flash-attn; y@W_proj
// B=2, T=2048, C=1024, H=16, HD=64.  I/O fp32; internal tensors bf16.
//
// R19 == R18 byte-identical (broker down again; R18 unmeasured).  Re-audited
// this round: staging XOR involution verified algebraically both sides,
// wave-uniform glds16 dests, no reg-staging state (R17's scratch-spill mode
// structurally impossible), LPT remap/diag-mask/Ps-no-barrier identical to
// measured R15.  Submitting unchanged for clean attribution.
//
// R18 change log (vs measured R15=284.36us / regressed R17=306.99us):
//  * attn reverted to R15 geometry (KVBLK=64, s[4], conditional diag mask,
//    grid 512, balanced LPT remap, no Ps barrier); K/V staging is now
//    global_load_lds(16B) into LINEAR XOR-swizzled LDS (gemm1's machinery):
//    LDS[row][slot] = G[row][slot ^ (row&7)]; reads XOR identically.
//    No staging VGPRs / ds_writes -> no scratch, no staging bank conflicts.
//  * setprio(1) around QK^T and PV MFMA clusters (semantically inert).
//  * gemm1/gemm2/rope/tp/cvt/trig byte-identical to R15.
// ---------------------------------------------------------------------------

typedef __attribute__((ext_vector_type(8))) short short8;   // 8 bf16 = 4 VGPRs
typedef __attribute__((ext_vector_type(4))) float floatx4;  // MFMA C/D frag

__device__ __forceinline__ ushort f2bf(float f) {
    unsigned x = __float_as_uint(f);
    x += 0x7fffu + ((x >> 16) & 1u);   // round-to-nearest-even
    return (ushort)(x >> 16);
}
__device__ __forceinline__ float bf2f(ushort u) {
    return __uint_as_float(((unsigned)u) << 16);
}

#define MFMA16(a, b, c) __builtin_amdgcn_mfma_f32_16x16x32_bf16((a), (b), (c), 0, 0, 0)

// async global->LDS, 16 bytes per lane.  LDS dest must be wave-uniform base;
// HW writes base + lane*16.  Global src is per-lane.
__device__ __forceinline__ void glds16(const ushort* g, ushort* l) {
    __builtin_amdgcn_global_load_lds(
        (const __attribute__((address_space(1))) unsigned int*)g,
        (__attribute__((address_space(3))) unsigned int*)l, 16, 0, 0);
}

// ---------------------------------------------------------------------------
// Transpose + cvt: src f32 [R][C] -> dst bf16 [C][R].  32x32 tiles via LDS.
// ---------------------------------------------------------------------------
__global__ __launch_bounds__(256) void tp_k(const float* __restrict__ src,
                                            ushort* __restrict__ dst,
                                            int R, int C) {
    __shared__ ushort t[32][34];
    const int c0 = blockIdx.x * 32, r0 = blockIdx.y * 32;
    const int tr = threadIdx.x >> 5, tc = threadIdx.x & 31;
#pragma unroll
    for (int j = 0; j < 4; j++)
        t[tr + j * 8][tc] = f2bf(src[(size_t)(r0 + tr + j * 8) * C + c0 + tc]);
    __syncthreads();
#pragma unroll
    for (int j = 0; j < 4; j++)
        dst[(size_t)(c0 + tr + j * 8) * R + r0 + tc] = t[tc][tr + j * 8];
}

// ---------------------------------------------------------------------------
// cvt: f32 -> bf16, 4 elems/thread.
// ---------------------------------------------------------------------------
__global__ __launch_bounds__(256) void cvt_k(const float* __restrict__ src,
                                             ushort* __restrict__ dst) {
    const size_t i = ((size_t)blockIdx.x * 256 + threadIdx.x) * 4;
    float4 t4 = *(const float4*)&src[i];
    *(ushort4*)&dst[i] = make_ushort4(f2bf(t4.x), f2bf(t4.y), f2bf(t4.z), f2bf(t4.w));
}

// ---------------------------------------------------------------------------
// trig table: tab[t][j] = (cos(t * 10000^(-j/32)), sin(...)), f64 math
// identical to the original in-rope computation (bit-identical results).
// ---------------------------------------------------------------------------
__global__ __launch_bounds__(256) void trig_k(float2* __restrict__ tab) {
    const int idx = blockIdx.x * 256 + threadIdx.x;   // [0, 65536)
    const int t = idx >> 5, j = idx & 31;
    const double inv = pow(10000.0, -(double)j / 32.0);
    const double ang = (double)t * inv;
    tab[idx] = make_float2((float)cos(ang), (float)sin(ang));
}

// ---------------------------------------------------------------------------
// GEMM1 (one batch): qkv = xb[2048][1024](bf16) @ WaT^T (Bt bf16 [3072][1024])
//   -> q: [H,T,HD]  k: [H,T,HD]  v^T: [H,HD,T]  (bf16)
// R15: 128(m)x64(n) tile, BK=64, global_load_lds staging, swizzled LDS.
// ---------------------------------------------------------------------------
__global__ __launch_bounds__(256, 3) void gemm1_qkv_k(const ushort* __restrict__ Ab,
                                                      const ushort* __restrict__ Bt,
                                                      ushort* __restrict__ qb,
                                                      ushort* __restrict__ kb,
                                                      ushort* __restrict__ vtb) {
    __shared__ __align__(16) ushort As[128 * 64];  // 16 KB, linear+swizzled
    __shared__ __align__(16) ushort Bs[64 * 64];   // 8 KB
    const int tid = threadIdx.x;
    const int m0 = blockIdx.y * 128, n0 = blockIdx.x * 64;
    const int w = tid >> 6, lane = tid & 63, quad = lane >> 4, l16 = lane & 15;
    const int wr = w >> 1, wc = w & 1;
    const int K = 1024;
    const int srow = lane >> 3, sslot = lane & 7;  // staging sub-row / slot

    floatx4 acc[4][2];
#pragma unroll
    for (int mt = 0; mt < 4; mt++)
#pragma unroll
        for (int nt = 0; nt < 2; nt++) acc[mt][nt] = (floatx4){0.f, 0.f, 0.f, 0.f};

    for (int k0 = 0; k0 < K; k0 += 64) {
        __syncthreads();   // all waves done reading prev tile
#pragma unroll
        for (int jj = 0; jj < 4; jj++) {
            const int reg = jj * 4 + w;
            const int row = reg * 8 + srow;
            const int cs = sslot ^ (row & 7);
            glds16(&Ab[(size_t)(m0 + row) * K + k0 + cs * 8], &As[reg * 512]);
        }
#pragma unroll
        for (int jj = 0; jj < 2; jj++) {
            const int reg = jj * 4 + w;
            const int row = reg * 8 + srow;
            const int cs = sslot ^ (row & 7);
            glds16(&Bt[(size_t)(n0 + row) * K + k0 + cs * 8], &Bs[reg * 512]);
        }
        __syncthreads();   // compiler drains vmcnt(0) before barrier

#pragma unroll
        for (int kk = 0; kk < 2; kk++) {
            short8 af[4], bfr[2];
#pragma unroll
            for (int mt = 0; mt < 4; mt++) {
                const int row = wr * 64 + mt * 16 + l16;
                const int slot = ((kk << 2) | quad) ^ (row & 7);
                af[mt] = *(short8*)&As[row * 64 + slot * 8];
            }
#pragma unroll
            for (int nt = 0; nt < 2; nt++) {
                const int row = wc * 32 + nt * 16 + l16;
                const int slot = ((kk << 2) | quad) ^ (row & 7);
                bfr[nt] = *(short8*)&Bs[row * 64 + slot * 8];
            }
#pragma unroll
            for (int mt = 0; mt < 4; mt++)
#pragma unroll
                for (int nt = 0; nt < 2; nt++) acc[mt][nt] = MFMA16(af[mt], bfr[nt], acc[mt][nt]);
        }
    }

    // Epilogue [R5-R10 verified formulas; nt bound 2, wave n-stride 32]
#pragma unroll
    for (int nt = 0; nt < 2; nt++) {
        const int n = n0 + wc * 32 + nt * 16 + l16;
        const int seg = n >> 10;          // 0=q 1=k 2=v
        const int cn = n & 1023;
        const int h = cn >> 6, d = cn & 63;
#pragma unroll
        for (int mt = 0; mt < 4; mt++) {
#pragma unroll
            for (int r = 0; r < 4; r++) {
                const int t = m0 + wr * 64 + mt * 16 + quad * 4 + r;
                const ushort v = f2bf(acc[mt][nt][r]);
                if (seg == 0)      qb[((size_t)h * 2048 + t) * 64 + d] = v;
                else if (seg == 1) kb[((size_t)h * 2048 + t) * 64 + d] = v;
                else               vtb[((size_t)h * 64 + d) * 2048 + t] = v;
            }
        }
    }
}

// ---------------------------------------------------------------------------
// RoPE (roll variant), table-based trig.  Math identical to verified R5-R11.
// ---------------------------------------------------------------------------
__global__ __launch_bounds__(256) void rope_k(ushort* __restrict__ q,
                                              ushort* __restrict__ k,
                                              const float2* __restrict__ tab) {
    const int wid = blockIdx.x * 4 + (threadIdx.x >> 6);  // row = h*2048 + t
    const int lane = threadIdx.x & 63;
    const int t = wid & 2047;
    const float2 cs = tab[t * 32 + (lane & 31)];
    const float c = cs.x;
    const float s = cs.y;
    const size_t base = (size_t)wid * 64;

    float qv = bf2f(q[base + lane]);
    float qp = __shfl(qv, (lane + 63) & 63, 64);
    q[base + lane] = f2bf(qv * c + qp * s);

    float kv = bf2f(k[base + lane]);
    float kp = __shfl(kv, (lane + 63) & 63, 64);
    k[base + lane] = f2bf(kv * c + kp * s);
}

// ---------------------------------------------------------------------------
// Flash attention (causal), transposed form.  [R10-verified frag math]
// R12: one q-tile per block (grid 512) -> 2 blocks/CU.
// R13: no barrier between per-wave Ps write/read.
// R14: balanced qt remap (CU pairs sum to const 17 tiles).
// R18: KVBLK=64 (R15-measured geometry); K/V staged via global_load_lds(16B)
//      into linear XOR-swizzled LDS: LDS[row][slot] = G[row][slot^(row&7)];
//      reads XOR identically.  setprio(1) around both MFMA clusters (T5).
// ---------------------------------------------------------------------------
__global__ __launch_bounds__(256, 2) void attn_k(const ushort* __restrict__ q,
                                                 const ushort* __restrict__ k,
                                                 const ushort* __restrict__ vt,
                                                 ushort* __restrict__ y) {
    __shared__ __align__(16) ushort Ks[64 * 64];    // [key][d]  8 KB linear+swz
    __shared__ __align__(16) ushort Vs[64 * 64];    // [d][key]  8 KB linear+swz
    __shared__ __align__(16) ushort Ps[4][16][72];  // per-wave P^T [qrow][key]

    const int bid = blockIdx.x;
    // blocks 0..255: qt = 31,30,..,16 (16 heads each); 256..511: qt = 0,1,..,15
    const int qt = (bid < 256) ? (31 - (bid >> 4)) : ((bid >> 4) - 16);
    const int h = bid & 15;
    const int tid = threadIdx.x, w = tid >> 6, lane = tid & 63;
    const int quad = lane >> 4, l16 = lane & 15;
    const int srow = lane >> 3, sslot = lane & 7;   // staging sub-row / slot

    const int q0 = qt * 64;
    const int qrow = q0 + w * 16 + l16;

    short8 qa0, qa1;
    {
        const ushort* qp = q + ((size_t)h * 2048 + qrow) * 64 + quad * 8;
        qa0 = *(const short8*)(qp);
        qa1 = *(const short8*)(qp + 32);
    }

    floatx4 O[4];
#pragma unroll
    for (int dt = 0; dt < 4; dt++) O[dt] = (floatx4){0.f, 0.f, 0.f, 0.f};
    float M = -30000.f, L = 0.f;

    for (int kt = 0; kt <= qt; kt++) {
        const int kbase = kt * 64;
        __syncthreads();   // all waves done reading prev tile's LDS
        // stage K[64][64] and V^T[64][64]: wave w covers 8-row regions w, 4+w.
        // global chunk cs = sslot ^ (row&7); LDS stays linear (glds16 dest is
        // wave-uniform base + lane*16).
#pragma unroll
        for (int jj = 0; jj < 2; jj++) {
            const int reg = jj * 4 + w;
            const int row = reg * 8 + srow;
            const int cs = sslot ^ (row & 7);
            glds16(&k[((size_t)h * 2048 + kbase + row) * 64 + cs * 8], &Ks[reg * 512]);
            glds16(&vt[((size_t)h * 64 + row) * 2048 + kbase + cs * 8], &Vs[reg * 512]);
        }
        __syncthreads();   // staging complete (vmcnt(0) drained at barrier)

        floatx4 s[4];
        __builtin_amdgcn_s_setprio(1);   // T5: QK^T MFMA cluster
#pragma unroll
        for (int nt = 0; nt < 4; nt++) {
            const int row = nt * 16 + l16;
            short8 ka0 = *(short8*)&Ks[row * 64 + ((quad ^ (row & 7)) * 8)];
            short8 ka1 = *(short8*)&Ks[row * 64 + (((4 | quad) ^ (row & 7)) * 8)];
            floatx4 z = (floatx4){0.f, 0.f, 0.f, 0.f};
            z = MFMA16(ka0, qa0, z);
            z = MFMA16(ka1, qa1, z);
            s[nt] = z;
        }
        __builtin_amdgcn_s_setprio(0);

        const bool diag = (kt == qt);
#pragma unroll
        for (int nt = 0; nt < 4; nt++)
#pragma unroll
            for (int r = 0; r < 4; r++) {
                float vv = s[nt][r] * 0.125f;
                if (diag) {
                    const int kidx = kbase + nt * 16 + quad * 4 + r;
                    if (kidx > qrow) vv = -30000.f;
                }
                s[nt][r] = vv;
            }

        float mx = -30000.f;
#pragma unroll
        for (int nt = 0; nt < 4; nt++)
#pragma unroll
            for (int r = 0; r < 4; r++) mx = fmaxf(mx, s[nt][r]);
        mx = fmaxf(mx, __shfl_xor(mx, 16, 64));
        mx = fmaxf(mx, __shfl_xor(mx, 32, 64));
        const float Mn = fmaxf(M, mx);
        const float alpha = __expf(M - Mn);
        float sum = 0.f;
#pragma unroll
        for (int nt = 0; nt < 4; nt++)
#pragma unroll
            for (int r = 0; r < 4; r++) {
                float pv = __expf(s[nt][r] - Mn);
                s[nt][r] = pv;
                sum += pv;
            }
        sum += __shfl_xor(sum, 16, 64);
        sum += __shfl_xor(sum, 32, 64);
        L = L * alpha + sum;
        M = Mn;
#pragma unroll
        for (int dt = 0; dt < 4; dt++) O[dt] *= alpha;

#pragma unroll
        for (int nt = 0; nt < 4; nt++) {
            ushort4 pk = make_ushort4(f2bf(s[nt][0]), f2bf(s[nt][1]),
                                      f2bf(s[nt][2]), f2bf(s[nt][3]));
            *(ushort4*)&Ps[w][l16][nt * 16 + quad * 4] = pk;
        }
        // no barrier: Ps[w] is written and read only by wave w; in-wave DS
        // ordering is enforced by the compiler's lgkmcnt tracking.

        short8 pb0 = *(short8*)&Ps[w][l16][quad * 8];
        short8 pb1 = *(short8*)&Ps[w][l16][32 + quad * 8];
        __builtin_amdgcn_s_setprio(1);   // T5: PV MFMA cluster
#pragma unroll
        for (int dt = 0; dt < 4; dt++) {
            const int row = dt * 16 + l16;
            short8 va0 = *(short8*)&Vs[row * 64 + ((quad ^ (row & 7)) * 8)];
            short8 va1 = *(short8*)&Vs[row * 64 + (((4 | quad) ^ (row & 7)) * 8)];
            O[dt] = MFMA16(va0, pb0, O[dt]);
            O[dt] = MFMA16(va1, pb1, O[dt]);
        }
        __builtin_amdgcn_s_setprio(0);
    }

    const float rl = 1.0f / L;
#pragma unroll
    for (int dt = 0; dt < 4; dt++) {
        ushort4 o4 = make_ushort4(f2bf(O[dt][0] * rl), f2bf(O[dt][1] * rl),
                                  f2bf(O[dt][2] * rl), f2bf(O[dt][3] * rl));
        *(ushort4*)&y[(size_t)qrow * 1024 + h * 64 + dt * 16 + quad * 4] = o4;
    }
}

// ---------------------------------------------------------------------------
// GEMM2 (one batch): out(f32) = y[2048][1024](bf16) @ WpT^T (bf16 [1024][1024])
// R15: 64x64 tile (grid 16x32 = 512 blocks = 2/CU), BK=64, global_load_lds
// staging, swizzled LDS — same machinery as gemm1.
// ---------------------------------------------------------------------------
__global__ __launch_bounds__(256, 2) void gemm2_proj_k(const ushort* __restrict__ Y,
                                                       const ushort* __restrict__ Bt,
                                                       float* __restrict__ out) {
    __shared__ __align__(16) ushort As[64 * 64];   // 8 KB, linear+swizzled
    __shared__ __align__(16) ushort Bs[64 * 64];   // 8 KB
    const int tid = threadIdx.x;
    const int m0 = blockIdx.y * 64, n0 = blockIdx.x * 64;
    const int w = tid >> 6, lane = tid & 63, quad = lane >> 4, l16 = lane & 15;
    const int wr = w >> 1, wc = w & 1;
    const int K = 1024;
    const int srow = lane >> 3, sslot = lane & 7;

    floatx4 acc[2][2];
#pragma unroll
    for (int mt = 0; mt < 2; mt++)
#pragma unroll
        for (int nt = 0; nt < 2; nt++) acc[mt][nt] = (floatx4){0.f, 0.f, 0.f, 0.f};

    for (int k0 = 0; k0 < K; k0 += 64) {
        __syncthreads();
#pragma unroll
        for (int jj = 0; jj < 2; jj++) {
            const int reg = jj * 4 + w;
            const int row = reg * 8 + srow;
            const int cs = sslot ^ (row & 7);
            glds16(&Y[(size_t)(m0 + row) * K + k0 + cs * 8], &As[reg * 512]);
            glds16(&Bt[(size_t)(n0 + row) * K + k0 + cs * 8], &Bs[reg * 512]);
        }
        __syncthreads();

#pragma unroll
        for (int kk = 0; kk < 2; kk++) {
            short8 af[2], bfr[2];
#pragma unroll
            for (int mt = 0; mt < 2; mt++) {
                const int row = wr * 32 + mt * 16 + l16;
                const int slot = ((kk << 2) | quad) ^ (row & 7);
                af[mt] = *(short8*)&As[row * 64 + slot * 8];
            }
#pragma unroll
            for (int nt = 0; nt < 2; nt++) {
                const int row = wc * 32 + nt * 16 + l16;
                const int slot = ((kk << 2) | quad) ^ (row & 7);
                bfr[nt] = *(short8*)&Bs[row * 64 + slot * 8];
            }
#pragma unroll
            for (int mt = 0; mt < 2; mt++)
#pragma unroll
                for (int nt = 0; nt < 2; nt++) acc[mt][nt] = MFMA16(af[mt], bfr[nt], acc[mt][nt]);
        }
    }

#pragma unroll
    for (int mt = 0; mt < 2; mt++)
#pragma unroll
        for (int nt = 0; nt < 2; nt++) {
            const int n = n0 + wc * 32 + nt * 16 + l16;
#pragma unroll
            for (int r = 0; r < 4; r++) {
                const int m = m0 + wr * 32 + mt * 16 + quad * 4 + r;
                out[(size_t)m * 1024 + n] = acc[mt][nt][r];
            }
        }
}

// ---------------------------------------------------------------------------
extern "C" void kernel_launch(void* const* d_in, const int* in_sizes, int n_in,
                              void* d_out, int out_size, void* d_ws, size_t ws_size,
                              hipStream_t stream) {
    const float* x  = (const float*)d_in[0];   // [2,2048,1024] f32
    const float* Wa = (const float*)d_in[1];   // [1024,3072]  f32
    const float* Wp = (const float*)d_in[2];   // [1024,1024]  f32
    float* out = (float*)d_out;                // [2,2048,1024] f32

    const size_t PB = (size_t)2048 * 1024;     // per-batch elements
    ushort* qb  = (ushort*)d_ws;               // 4 MB bf16 q  [H,T,HD]
    ushort* kb  = qb + PB;                     // 4 MB bf16 k  [H,T,HD]
    ushort* vtb = kb + PB;                     // 4 MB bf16 v^T[H,HD,T]
    ushort* yb  = vtb + PB;                    // 4 MB bf16 y [T,C] / x_bf16
    ushort* wtA = (ushort*)(out + PB);         // 6 MB W_attn^T bf16 (d_out b1
                                               //  half; dead until gemm2-b1,
                                               //  which fully overwrites it)
    float2* tab = (float2*)(wtA + (size_t)3 * 1024 * 1024);
                                               // 512 KB trig table, bytes
                                               //  [14MB,14.5MB) of d_out; last
                                               //  read by rope-b1, overwritten
                                               //  only by gemm2-b1

    // W_proj^T: hoisted to stable ws tail (d_ws+16MB) when it fits; else the
    // per-batch qb-slot path (wtP regenerated each batch, over dead q).
    const bool hoistWp = ws_size >= (size_t)18 * 1024 * 1024;
    ushort* wtP_stable = yb + PB;              // d_ws + 16MB (only if hoistWp)

    tp_k<<<dim3(96, 32), 256, 0, stream>>>(Wa, wtA, 1024, 3072);
    trig_k<<<dim3(256), 256, 0, stream>>>(tab);
    if (hoistWp)
        tp_k<<<dim3(32, 32), 256, 0, stream>>>(Wp, wtP_stable, 1024, 1024);

    for (int b = 0; b < 2; b++) {
        cvt_k<<<dim3(2048), 256, 0, stream>>>(x + b * PB, yb);        // xb in yb slot
        gemm1_qkv_k<<<dim3(48, 16), 256, 0, stream>>>(yb, wtA, qb, kb, vtb);
        rope_k<<<dim3(8192), 256, 0, stream>>>(qb, kb, tab);
        attn_k<<<dim3(512), 256, 0, stream>>>(qb, kb, vtb, yb);       // y over xb
        if (hoistWp) {
            gemm2_proj_k<<<dim3(16, 32), 256, 0, stream>>>(yb, wtP_stable, out + b * PB);
        } else {
            tp_k<<<dim3(32, 32), 256, 0, stream>>>(Wp, qb, 1024, 1024);  // over dead q
            gemm2_proj_k<<<dim3(16, 32), 256, 0, stream>>>(yb, qb, out + b * PB);
        }
    }
}